// Round 12
// baseline (68.925 us; speedup 1.0000x reference)
//
#include <hip/hip_runtime.h>
#include <hip/hip_bf16.h>

// Problem constants:
//   X: (B=16, D=512, 60, 60) fp32 -> N = 3600
//   codewords: (K=32, D=512) fp32, scale: (K=32,) fp32
//   out E: (B, K, D) fp32
constexpr int BB = 16;
constexpr int DD = 512;
constexpr int NN = 3600;
constexpr int KK = 32;
constexpr int NP = 3712;      // padded N (58 tiles of 64)
constexpr int TIL = 58;       // K1 n-tiles of 64 per b
constexpr int NSTEP = 113;    // ceil(3600/32) K2 n-steps (beyond 3600 At==0)
constexpr int SP2 = 16;       // K2 n-splits
constexpr int DC = 8;         // K2 d-chunks of 64

typedef __attribute__((ext_vector_type(8))) short short8;
typedef __attribute__((ext_vector_type(4))) float f32x4;

__device__ inline unsigned bf16pack(float a, float b) {
    unsigned ia = __float_as_uint(a), ib = __float_as_uint(b);
    ia = (ia + 0x7fffu + ((ia >> 16) & 1u)) >> 16;          // RNE to bf16
    ib = (ib + 0x7fffu + ((ib >> 16) & 1u)) & 0xffff0000u;
    return ia | ib;
}

// ---------------------------------------------------------------------------
// K0: Cbf[k][d] = bf16(Cw[k][d]);  sc2[k] = scale[k]*sum_d C[k,d]^2
// ---------------------------------------------------------------------------
__global__ __launch_bounds__(256) void k0_prep(const float* __restrict__ Cw,
                                               const float* __restrict__ scale,
                                               ushort* __restrict__ Cbf,
                                               float* __restrict__ sc2) {
    __shared__ float buf[8][32];
    const int t = threadIdx.x;
    const int k = t & 31;
    const int h = t >> 5;   // 0..7, 64 d's each
    const float4* row = reinterpret_cast<const float4*>(Cw + k * DD + h * 64);
    uint2* crow = reinterpret_cast<uint2*>(Cbf + k * DD + h * 64);
    float s = 0.f;
#pragma unroll
    for (int j = 0; j < 16; ++j) {
        float4 v = row[j];
        crow[j] = make_uint2(bf16pack(v.x, v.y), bf16pack(v.z, v.w));
        s += v.x * v.x + v.y * v.y + v.z * v.z + v.w * v.w;
    }
    buf[h][k] = s;
    __syncthreads();
    if (t < 32) {
        float tot = 0.f;
#pragma unroll
        for (int j = 0; j < 8; ++j) tot += buf[j][t];
        sc2[t] = scale[t] * tot;
    }
}

// ---------------------------------------------------------------------------
// K1: GEMM1 (xc = X^T C^T) + softmax, all in registers, no LDS, no barriers.
// Grid: B*TIL = 928 blocks x 256 threads; each wave owns 16 n, fully
// independent (max MLP). Deep unroll keeps ~32 scalar loads in flight.
// Writes At[b][k][n] bf16 (zero-padded to NP) and per-wave Asum partials.
// ---------------------------------------------------------------------------
__global__ __launch_bounds__(256) void k1_gemm1(const float* __restrict__ X,
                                                const ushort* __restrict__ Cbf,
                                                const float* __restrict__ scale,
                                                const float* __restrict__ sc2,
                                                ushort* __restrict__ At,
                                                float* __restrict__ asum_part) {
    const int t = threadIdx.x;
    const int w = t >> 6;
    const int l = t & 63;
    const int q = l >> 4;     // 0..3
    const int r = l & 15;     // 0..15
    const int bi = blockIdx.x;
    const int b = bi / TIL;
    const int tile = bi % TIL;
    const int nbase = tile * 64 + w * 16;
    const int nrow = nbase + r;                 // A-frag row (n)
    const int nc = (nrow < NN) ? nrow : (NN - 1);

    const float* Xp = X + (size_t)b * DD * NN + (size_t)(q * 8) * NN + nc;
    const ushort* cb0 = Cbf + r * DD + q * 8;
    const ushort* cb1 = cb0 + 16 * DD;

    f32x4 acc0 = {0.f, 0.f, 0.f, 0.f};
    f32x4 acc1 = {0.f, 0.f, 0.f, 0.f};
    float x2p = 0.f;

#pragma unroll 4
    for (int s = 0; s < 16; ++s) {
        float xv[8];
#pragma unroll
        for (int j = 0; j < 8; ++j) xv[j] = Xp[(size_t)(s * 32 + j) * NN];
#pragma unroll
        for (int j = 0; j < 8; ++j) x2p = fmaf(xv[j], xv[j], x2p);
        union { short8 s8; unsigned u[4]; } a;
        a.u[0] = bf16pack(xv[0], xv[1]);
        a.u[1] = bf16pack(xv[2], xv[3]);
        a.u[2] = bf16pack(xv[4], xv[5]);
        a.u[3] = bf16pack(xv[6], xv[7]);
        const short8 b0 = *reinterpret_cast<const short8*>(cb0 + s * 32);
        const short8 b1 = *reinterpret_cast<const short8*>(cb1 + s * 32);
        acc0 = __builtin_amdgcn_mfma_f32_16x16x32_bf16(a.s8, b0, acc0, 0, 0, 0);
        acc1 = __builtin_amdgcn_mfma_f32_16x16x32_bf16(a.s8, b1, acc1, 0, 0, 0);
    }

    // x2[nbase + r] = full d-sum (reduce the 4 q-partials)
    float x2f = x2p;
    x2f += __shfl_xor(x2f, 16);
    x2f += __shfl_xor(x2f, 32);

    // softmax: lane (q,r) holds xc for n = nbase + 4q + i, k = r / r+16
    const float sk0 = scale[r], sk1 = scale[r + 16];
    const float sq0 = sc2[r],  sq1 = sc2[r + 16];
    float e0v[4], e1v[4];
    float as0 = 0.f, as1 = 0.f;
#pragma unroll
    for (int i = 0; i < 4; ++i) {
        const float x2v = __shfl(x2f, 4 * q + i);   // lane 4q+i holds x2[nbase+4q+i]
        float sl0 = fmaf(sk0, x2v, sq0) - 2.f * sk0 * acc0[i];
        float sl1 = fmaf(sk1, x2v, sq1) - 2.f * sk1 * acc1[i];
        float m = fmaxf(sl0, sl1);
        m = fmaxf(m, __shfl_xor(m, 1));
        m = fmaxf(m, __shfl_xor(m, 2));
        m = fmaxf(m, __shfl_xor(m, 4));
        m = fmaxf(m, __shfl_xor(m, 8));
        float e0 = __expf(sl0 - m), e1 = __expf(sl1 - m);
        float ssum = e0 + e1;
        ssum += __shfl_xor(ssum, 1);
        ssum += __shfl_xor(ssum, 2);
        ssum += __shfl_xor(ssum, 4);
        ssum += __shfl_xor(ssum, 8);
        const float inv = 1.f / ssum;
        e0 *= inv; e1 *= inv;
        if (nbase + 4 * q + i >= NN) { e0 = 0.f; e1 = 0.f; }
        e0v[i] = e0; e1v[i] = e1;
        as0 += e0; as1 += e1;
    }

    // At[b][k][n] bf16 writes (4 n's packed per lane per k)
    uint2 w0 = make_uint2(bf16pack(e0v[0], e0v[1]), bf16pack(e0v[2], e0v[3]));
    uint2 w1 = make_uint2(bf16pack(e1v[0], e1v[1]), bf16pack(e1v[2], e1v[3]));
    *reinterpret_cast<uint2*>(At + ((size_t)b * KK + r) * NP + nbase + 4 * q) = w0;
    *reinterpret_cast<uint2*>(At + ((size_t)b * KK + r + 16) * NP + nbase + 4 * q) = w1;

    // per-wave Asum partials
    as0 += __shfl_xor(as0, 16); as0 += __shfl_xor(as0, 32);
    as1 += __shfl_xor(as1, 16); as1 += __shfl_xor(as1, 32);
    if (l < 16) {
        asum_part[((size_t)bi * 4 + w) * KK + r] = as0;
        asum_part[((size_t)bi * 4 + w) * KK + r + 16] = as1;
    }
}

// ---------------------------------------------------------------------------
// K2: GEMM2 partials Ep[sp][b][k][d] = sum_{n in split} At[k][n]*X[d][n].
// Grid: b(16) x dchunk(8, 64 d each) x split(16) = 2048 blocks x 256 threads.
// A-op: At bf16 direct (16B/lane). B-op: X fp32 direct (2 float4, L3-hot
// after K1) + pack. No LDS, no barriers; 8 waves/SIMD.
// ---------------------------------------------------------------------------
__global__ __launch_bounds__(256) void k2_gemm2(const float* __restrict__ X,
                                                const ushort* __restrict__ At,
                                                float* __restrict__ Ep) {
    const int t = threadIdx.x;
    const int w = t >> 6;
    const int l = t & 63;
    const int q = l >> 4;
    const int r = l & 15;
    const int bid = blockIdx.x;
    const int sp = bid & 15;
    const int dc = (bid >> 4) & 7;
    const int b = bid >> 7;

    constexpr int QS = NSTEP / SP2, RS = NSTEP % SP2;   // 7, 1
    const int s0 = sp * QS + (sp < RS ? sp : RS);
    const int s1 = s0 + QS + (sp < RS ? 1 : 0);

    const int d = dc * 64 + w * 16 + r;                 // B-frag col
    const float* Xp = X + ((size_t)b * DD + d) * NN;
    const ushort* a0p = At + ((size_t)b * KK + r) * NP + q * 8;
    const ushort* a1p = a0p + (size_t)16 * NP;

    f32x4 acc0 = {0.f, 0.f, 0.f, 0.f};
    f32x4 acc1 = {0.f, 0.f, 0.f, 0.f};

#pragma unroll 2
    for (int s = s0; s < s1; ++s) {
        int off = s * 32 + q * 8;
        if (off > NN - 8) off = NN - 8;   // only all-invalid groups clamp (At==0 there)
        const float4 f0 = *reinterpret_cast<const float4*>(Xp + off);
        const float4 f1 = *reinterpret_cast<const float4*>(Xp + off + 4);
        union { short8 s8; unsigned u[4]; } bb;
        bb.u[0] = bf16pack(f0.x, f0.y);
        bb.u[1] = bf16pack(f0.z, f0.w);
        bb.u[2] = bf16pack(f1.x, f1.y);
        bb.u[3] = bf16pack(f1.z, f1.w);
        const short8 a0 = *reinterpret_cast<const short8*>(a0p + s * 32);
        const short8 a1 = *reinterpret_cast<const short8*>(a1p + s * 32);
        acc0 = __builtin_amdgcn_mfma_f32_16x16x32_bf16(a0, bb.s8, acc0, 0, 0, 0);
        acc1 = __builtin_amdgcn_mfma_f32_16x16x32_bf16(a1, bb.s8, acc1, 0, 0, 0);
    }

    // store: D-frag row = k-local (q*4+i), col = d
    float* ep = Ep + ((size_t)sp * BB + b) * KK * DD + d;
#pragma unroll
    for (int i = 0; i < 4; ++i) {
        ep[(size_t)(q * 4 + i) * DD] = acc0[i];
        ep[(size_t)(16 + q * 4 + i) * DD] = acc1[i];
    }
}

// ---------------------------------------------------------------------------
// K3: E[b,k,d] = sum_sp Ep[sp][b,k,d] - Asum[b,k]*C[k,d]
// Grid: B*K = 512 blocks x 256 threads (float4 per lane, 128 lanes active).
// ---------------------------------------------------------------------------
__global__ __launch_bounds__(256) void k3_final(const float* __restrict__ Ep,
                                                const float* __restrict__ asum_part,
                                                const float* __restrict__ Cw,
                                                float* __restrict__ E) {
    __shared__ float red[256];
    const int t = threadIdx.x;
    const int bk = blockIdx.x;
    const int b = bk >> 5, k = bk & 31;

    // Asum[b][k]: 58 tiles * 4 waves = 232 partials
    float v = 0.f;
    if (t < TIL * 4) v = asum_part[((size_t)b * TIL * 4 + t) * KK + k];
    red[t] = v;
    __syncthreads();
#pragma unroll
    for (int s = 128; s > 0; s >>= 1) {
        if (t < s) red[t] += red[t + s];
        __syncthreads();
    }
    const float asum = red[0];

    if (t < 128) {
        const int d = t * 4;
        float4 sv = make_float4(0.f, 0.f, 0.f, 0.f);
#pragma unroll
        for (int sp = 0; sp < SP2; ++sp) {
            const float4 vv = *reinterpret_cast<const float4*>(
                Ep + (((size_t)sp * BB + b) * KK + k) * DD + d);
            sv.x += vv.x; sv.y += vv.y; sv.z += vv.z; sv.w += vv.w;
        }
        const float4 c = *reinterpret_cast<const float4*>(Cw + k * DD + d);
        float4 o;
        o.x = sv.x - asum * c.x;
        o.y = sv.y - asum * c.y;
        o.z = sv.z - asum * c.z;
        o.w = sv.w - asum * c.w;
        *reinterpret_cast<float4*>(E + ((size_t)b * KK + k) * DD + d) = o;
    }
}

// ---------------------------------------------------------------------------
extern "C" void kernel_launch(void* const* d_in, const int* in_sizes, int n_in,
                              void* d_out, int out_size, void* d_ws, size_t ws_size,
                              hipStream_t stream) {
    const float* X     = (const float*)d_in[0];
    const float* Cw    = (const float*)d_in[1];
    const float* scale = (const float*)d_in[2];
    float* E = (float*)d_out;

    // ws layout (float slots):
    //   At        : 16*32*3712 ushort = 950,272 float slots
    //   asum      : 928*4*32          = 118,784
    //   sc2       : 32
    //   Cbf       : 32*512 ushort     = 8,192 float slots
    //   Ep        : 16*16*32*512      = 4,194,304           (~21 MB total)
    float* ws = (float*)d_ws;
    ushort* At = (ushort*)ws;
    float* asum_part = ws + 950272;
    float* sc2 = asum_part + 118784;
    ushort* Cbf = (ushort*)(sc2 + KK);
    float* Ep = sc2 + KK + 8192;

    k0_prep<<<dim3(1), dim3(256), 0, stream>>>(Cw, scale, Cbf, sc2);
    k1_gemm1<<<dim3(BB * TIL), dim3(256), 0, stream>>>(X, Cbf, scale, sc2, At, asum_part);
    k2_gemm2<<<dim3(BB * DC * SP2), dim3(256), 0, stream>>>(X, At, Ep);
    k3_final<<<dim3(BB * KK), dim3(256), 0, stream>>>(Ep, asum_part, Cw, E);
}